// Round 1
// baseline (304.960 us; speedup 1.0000x reference)
//
#include <hip/hip_runtime.h>
#include <cstdint>

typedef unsigned short u16;
typedef float f32x4 __attribute__((ext_vector_type(4)));
typedef __bf16 bf16x8 __attribute__((ext_vector_type(8)));
typedef u16 u16x8 __attribute__((ext_vector_type(8)));

// ---------- helpers ----------
__device__ __forceinline__ u16 f2bf(float f) {
  uint32_t u = __float_as_uint(f);
  u += 0x7fffu + ((u >> 16) & 1u);   // RNE
  return (u16)(u >> 16);
}
__device__ __forceinline__ float bf2f(u16 s) {
  return __uint_as_float(((uint32_t)s) << 16);
}

// global -> LDS direct copy, 16B per lane (CK-style address-space casts)
__device__ __forceinline__ void ld16(const u16* g, u16* l) {
  auto* gp = reinterpret_cast<const __attribute__((address_space(1))) u16*>(
      reinterpret_cast<uintptr_t>(g));
  auto* lp = reinterpret_cast<__attribute__((address_space(3))) u16*>(
      static_cast<uint32_t>(reinterpret_cast<uintptr_t>(l)));
  __builtin_amdgcn_global_load_lds(gp, lp, 16, 0, 0);
}

__device__ __forceinline__ f32x4 mfma16(u16x8 a, u16x8 b, f32x4 c) {
  return __builtin_amdgcn_mfma_f32_16x16x32_bf16(
      __builtin_bit_cast(bf16x8, a), __builtin_bit_cast(bf16x8, b), c, 0, 0, 0);
}

__device__ __forceinline__ float sigmoidf_(float x) { return 1.f / (1.f + __expf(-x)); }
__device__ __forceinline__ float siluf_(float x) { return x * sigmoidf_(x); }
__device__ __forceinline__ float softplusf_(float x) {
  return fmaxf(x, 0.f) + log1pf(__expf(-fabsf(x)));
}

// ---------- weight packing ----------
#define PACK_TOT 6651904
__global__ __launch_bounds__(256) void pack_kernel(
    const float* __restrict__ skip_w, const float* __restrict__ in_w,
    const float* __restrict__ out_w, const float* __restrict__ wd2,
    const float* __restrict__ wd1, const float* __restrict__ wb,
    const float* __restrict__ wc, const float* __restrict__ A_log,
    u16* __restrict__ skipw_bf, u16* __restrict__ inw_bf, u16* __restrict__ outw_bf,
    u16* __restrict__ wd2_bf, u16* __restrict__ w96, float* __restrict__ Aneg) {
  int stride = gridDim.x * 256;
  for (int i = blockIdx.x * 256 + threadIdx.x; i < PACK_TOT; i += stride) {
    int j = i;
    if (j < 2097152) { skipw_bf[j] = f2bf(skip_w[j]); continue; } j -= 2097152;
    if (j < 2097152) { inw_bf[j] = f2bf(in_w[j]); continue; } j -= 2097152;
    if (j < 2097152) { outw_bf[j] = f2bf(out_w[j]); continue; } j -= 2097152;
    if (j < 131072)  { wd2_bf[j] = f2bf(wd2[j]); continue; } j -= 131072;
    if (j < 131072)  { w96[j] = f2bf(wd1[j]); continue; } j -= 131072;
    if (j < 32768)   { w96[131072 + j] = f2bf(wb[j]); continue; } j -= 32768;
    if (j < 32768)   { w96[163840 + j] = f2bf(wc[j]); continue; } j -= 32768;
    Aneg[j] = -__expf(A_log[j]);
  }
}

// ---------- RMSNorm ----------
__global__ __launch_bounds__(256) void rmsnorm_kernel(
    const float* __restrict__ x, const float* __restrict__ w, u16* __restrict__ out) {
  int row = blockIdx.x, t = threadIdx.x;
  const float4* xr = (const float4*)(x + (size_t)row * 1024);
  float4 v = xr[t];
  float ss = v.x * v.x + v.y * v.y + v.z * v.z + v.w * v.w;
  for (int o = 32; o > 0; o >>= 1) ss += __shfl_xor(ss, o);
  __shared__ float wsum[4];
  if ((t & 63) == 0) wsum[t >> 6] = ss;
  __syncthreads();
  float tot = wsum[0] + wsum[1] + wsum[2] + wsum[3];
  float rs = rsqrtf(tot * (1.0f / 1024.0f) + 1e-5f);
  float4 wv = ((const float4*)w)[t];
  uint2 pk;
  pk.x = (uint32_t)f2bf(v.x * rs * wv.x) | ((uint32_t)f2bf(v.y * rs * wv.y) << 16);
  pk.y = (uint32_t)f2bf(v.z * rs * wv.z) | ((uint32_t)f2bf(v.w * rs * wv.w) << 16);
  ((uint2*)out)[row * 256 + t] = pk;
}

// ---------- MFMA GEMM: C = A(MxK,bf16) * B(NxK,bf16)^T ----------
// EPI 0: n<Nsplit -> bf16 C0 (ld Nsplit); else fp32 C1 (ld N-Nsplit)   [skip|xin]
// EPI 1: softplus(acc + bias[n]) -> fp32 C0                            [delta]
// EPI 2: addsrc + acc -> fp32 C0                                       [output]
template <int BM, int BN, int EPI>
__global__ __launch_bounds__(256) void gemm_bt(
    const u16* __restrict__ A, const u16* __restrict__ B0, const u16* __restrict__ B1,
    int M, int N, int K, int Nsplit,
    void* __restrict__ C0, void* __restrict__ C1,
    const float* __restrict__ bias, const float* __restrict__ addsrc) {
  constexpr int TM = BM / 32, TN = BN / 32;
  __shared__ __align__(16) u16 sA[BM * 32];
  __shared__ __align__(16) u16 sB[BN * 32];
  const int t = threadIdx.x;
  const int lane = t & 63, wid = t >> 6;
  const int wm = wid >> 1, wn = wid & 1;
  const int mBase = blockIdx.y * BM;
  const int nBase = blockIdx.x * BN;
  const bool hi = (nBase >= Nsplit);
  const u16* Bp = hi ? B1 : B0;
  const int nB0 = nBase - (hi ? Nsplit : 0);
  const int col = lane & 15, quad = lane >> 4;

  f32x4 acc[TM][TN];
#pragma unroll
  for (int i = 0; i < TM; ++i)
#pragma unroll
    for (int j = 0; j < TN; ++j) acc[i][j] = f32x4{0.f, 0.f, 0.f, 0.f};

  for (int k0 = 0; k0 < K; k0 += 32) {
#pragma unroll
    for (int c = t; c < BM * 4; c += 256) {
      int row = c >> 2, k8 = (c & 3) * 8;
      ld16(A + (size_t)(mBase + row) * K + k0 + k8, &sA[c * 8]);
    }
#pragma unroll
    for (int c = t; c < BN * 4; c += 256) {
      int row = c >> 2, k8 = (c & 3) * 8;
      ld16(Bp + (size_t)(nB0 + row) * K + k0 + k8, &sB[c * 8]);
    }
    __syncthreads();
    u16x8 af[TM], bfv[TN];
#pragma unroll
    for (int i = 0; i < TM; ++i)
      af[i] = *(const u16x8*)&sA[(wm * (BM / 2) + i * 16 + col) * 32 + quad * 8];
#pragma unroll
    for (int j = 0; j < TN; ++j)
      bfv[j] = *(const u16x8*)&sB[(wn * (BN / 2) + j * 16 + col) * 32 + quad * 8];
#pragma unroll
    for (int i = 0; i < TM; ++i)
#pragma unroll
      for (int j = 0; j < TN; ++j) acc[i][j] = mfma16(af[i], bfv[j], acc[i][j]);
    __syncthreads();
  }

#pragma unroll
  for (int i = 0; i < TM; ++i) {
#pragma unroll
    for (int j = 0; j < TN; ++j) {
#pragma unroll
      for (int r = 0; r < 4; ++r) {
        int gm = mBase + wm * (BM / 2) + i * 16 + quad * 4 + r;
        int gn = nBase + wn * (BN / 2) + j * 16 + col;
        float v = acc[i][j][r];
        if (EPI == 0) {
          if (gn < Nsplit)
            ((u16*)C0)[(size_t)gm * Nsplit + gn] = f2bf(v);
          else
            ((float*)C1)[(size_t)gm * (N - Nsplit) + (gn - Nsplit)] = v;
        } else if (EPI == 1) {
          ((float*)C0)[(size_t)gm * N + gn] = softplusf_(v + bias[gn]);
        } else {
          ((float*)C0)[(size_t)gm * N + gn] = addsrc[(size_t)gm * N + gn] + v;
        }
      }
    }
  }
}

// ---------- skinny GEMM: N=96 (wd1|wb|wc), cols 0..63 -> d1 bf16, 64..95 -> bc fp32
__global__ __launch_bounds__(256) void gemm_skinny(
    const u16* __restrict__ A, const u16* __restrict__ B,
    u16* __restrict__ d1_bf, float* __restrict__ bc, int K) {
  __shared__ __align__(16) u16 sA[64 * 32];
  __shared__ __align__(16) u16 sB[96 * 32];
  const int t = threadIdx.x, lane = t & 63, w = t >> 6;
  const int mBase = blockIdx.x * 64;
  const int col = lane & 15, quad = lane >> 4;
  f32x4 acc[6];
#pragma unroll
  for (int j = 0; j < 6; ++j) acc[j] = f32x4{0.f, 0.f, 0.f, 0.f};

  for (int k0 = 0; k0 < K; k0 += 32) {
    for (int c = t; c < 640; c += 256) {
      if (c < 256) {
        int row = c >> 2, k8 = (c & 3) * 8;
        ld16(A + (size_t)(mBase + row) * K + k0 + k8, &sA[c * 8]);
      } else {
        int cb = c - 256;
        int row = cb >> 2, k8 = (cb & 3) * 8;
        ld16(B + (size_t)row * K + k0 + k8, &sB[cb * 8]);
      }
    }
    __syncthreads();
    u16x8 af = *(const u16x8*)&sA[(w * 16 + col) * 32 + quad * 8];
#pragma unroll
    for (int j = 0; j < 6; ++j) {
      u16x8 bfv = *(const u16x8*)&sB[(j * 16 + col) * 32 + quad * 8];
      acc[j] = mfma16(af, bfv, acc[j]);
    }
    __syncthreads();
  }
#pragma unroll
  for (int j = 0; j < 6; ++j)
#pragma unroll
    for (int r = 0; r < 4; ++r) {
      int gm = mBase + w * 16 + quad * 4 + r;
      int gn = j * 16 + col;
      float v = acc[j][r];
      if (gn < 64) d1_bf[gm * 64 + gn] = f2bf(v);
      else bc[gm * 32 + gn - 64] = v;
    }
}

// ---------- conv (causal depthwise K=4) + SiLU ----------
__global__ __launch_bounds__(256) void conv_silu_kernel(
    const float* __restrict__ xin, const float* __restrict__ conv_w,
    const float* __restrict__ conv_b, float* __restrict__ xconv,
    u16* __restrict__ xconv_bf) {
  int i = blockIdx.x * 256 + threadIdx.x;  // B*L*E exact
  int e = i & 2047;
  int l = (i >> 11) & 1023;
  float4 wv = ((const float4*)conv_w)[e];
  float acc = conv_b[e] + xin[i] * wv.w;
  if (l >= 1) acc += xin[i - 2048] * wv.z;
  if (l >= 2) acc += xin[i - 4096] * wv.y;
  if (l >= 3) acc += xin[i - 6144] * wv.x;
  float s = siluf_(acc);
  xconv[i] = s;
  xconv_bf[i] = f2bf(s);
}

// ---------- SSM scan: pass 1 (local states per 32-chunk) ----------
__global__ __launch_bounds__(256) void scan1_kernel(
    const float* __restrict__ delta, const float* __restrict__ xconv,
    const float* __restrict__ bc, const float* __restrict__ Aneg,
    float* __restrict__ hloc, float* __restrict__ Ssum) {
  int t = threadIdx.x;
  int e = blockIdx.x * 256 + t;
  int c = blockIdx.y, b = blockIdx.z;
  int m0 = b * 1024 + c * 32;
  __shared__ float sBC[1024];
  for (int j = t; j < 1024; j += 256) sBC[j] = bc[m0 * 32 + j];
  float Ar[16], h[16];
#pragma unroll
  for (int n = 0; n < 16; ++n) { Ar[n] = Aneg[e * 16 + n]; h[n] = 0.f; }
  float S = 0.f;
  __syncthreads();
  for (int l = 0; l < 32; ++l) {
    size_t m = (size_t)(m0 + l) * 2048 + e;
    float dt = delta[m], xv = xconv[m];
    S += dt;
    float dx = dt * xv;
    const float* bl = &sBC[l * 32];
#pragma unroll
    for (int n = 0; n < 16; ++n) h[n] = __expf(dt * Ar[n]) * h[n] + dx * bl[n];
  }
  size_t base = ((size_t)(b * 32 + c) * 2048 + e) * 16;
#pragma unroll
  for (int n = 0; n < 16; ++n) hloc[base + n] = h[n];
  Ssum[(b * 32 + c) * 2048 + e] = S;
}

// ---------- scan chunk combine (sequential over 32 chunks) ----------
__global__ __launch_bounds__(256) void combine_kernel(
    const float* __restrict__ Aneg, const float* __restrict__ Ssum,
    float* __restrict__ hloc) {
  int tid = blockIdx.x * 256 + threadIdx.x;  // 65536 = B*E*N
  int b = tid >> 15, r = tid & 32767;
  int e = r >> 4;
  float a = Aneg[r];
  float h = 0.f;
  for (int c = 0; c < 32; ++c) {
    size_t base = (size_t)(b * 32 + c) * 32768 + r;
    float hl = hloc[base];
    float S = Ssum[(b * 32 + c) * 2048 + e];
    hloc[base] = h;  // h_init for this chunk
    h = __expf(a * S) * h + hl;
  }
}

// ---------- scan pass 2: replay with h_init, fused gating epilogue ----------
__global__ __launch_bounds__(256) void scan2_kernel(
    const float* __restrict__ delta, const float* __restrict__ xconv,
    const float* __restrict__ bc, const float* __restrict__ Aneg,
    const float* __restrict__ hloc, const u16* __restrict__ skip_bf,
    const float* __restrict__ W_D, u16* __restrict__ yfin_bf) {
  int t = threadIdx.x;
  int e = blockIdx.x * 256 + t;
  int c = blockIdx.y, b = blockIdx.z;
  int m0 = b * 1024 + c * 32;
  __shared__ float sBC[1024];
  for (int j = t; j < 1024; j += 256) sBC[j] = bc[m0 * 32 + j];
  float Ar[16], h[16];
  size_t hbase = ((size_t)(b * 32 + c) * 2048 + e) * 16;
#pragma unroll
  for (int n = 0; n < 16; ++n) { Ar[n] = Aneg[e * 16 + n]; h[n] = hloc[hbase + n]; }
  float wd = W_D[e];
  __syncthreads();
  for (int l = 0; l < 32; ++l) {
    size_t m = (size_t)(m0 + l) * 2048 + e;
    float dt = delta[m], xv = xconv[m];
    float dx = dt * xv;
    const float* bl = &sBC[l * 32];
    float y = 0.f;
#pragma unroll
    for (int n = 0; n < 16; ++n) {
      h[n] = __expf(dt * Ar[n]) * h[n] + dx * bl[n];
      y += h[n] * bl[16 + n];
    }
    float yv = y + xv * wd;
    float sk = bf2f(skip_bf[m]);
    yv *= sk * sigmoidf_(sk);
    yfin_bf[m] = f2bf(yv);
  }
}

// ---------- launch ----------
extern "C" void kernel_launch(void* const* d_in, const int* in_sizes, int n_in,
                              void* d_out, int out_size, void* d_ws, size_t ws_size,
                              hipStream_t stream) {
  (void)in_sizes; (void)n_in; (void)out_size; (void)ws_size;
  const float* resid  = (const float*)d_in[0];
  const float* norm_w = (const float*)d_in[1];
  const float* skip_w = (const float*)d_in[2];
  const float* in_w   = (const float*)d_in[3];
  const float* conv_w = (const float*)d_in[4];
  const float* conv_b = (const float*)d_in[5];
  const float* wd1    = (const float*)d_in[6];
  const float* wd2    = (const float*)d_in[7];
  const float* wd2_b  = (const float*)d_in[8];
  const float* wb     = (const float*)d_in[9];
  const float* wc     = (const float*)d_in[10];
  const float* A_log  = (const float*)d_in[11];
  const float* W_D    = (const float*)d_in[12];
  const float* out_w  = (const float*)d_in[13];

  char* p = (char*)d_ws;
  u16*   skipw_bf = (u16*)(p + 0);
  u16*   inw_bf   = (u16*)(p + 4194304);
  u16*   outw_bf  = (u16*)(p + 8388608);
  u16*   wd2_bf   = (u16*)(p + 12582912);
  u16*   w96      = (u16*)(p + 12845056);
  float* Aneg     = (float*)(p + 13238272);
  u16*   xn_bf    = (u16*)(p + 13369344);
  u16*   skip_bf  = (u16*)(p + 17563648);
  float* xin      = (float*)(p + 25952256);
  float* xconv    = (float*)(p + 42729472);
  u16*   xconv_bf = (u16*)(p + 59506688);
  u16*   d1_bf    = (u16*)(p + 67895296);
  float* bc       = (float*)(p + 68157440);
  u16*   yfin_bf  = (u16*)(p + 68419584);
  float* hloc     = (float*)(p + 76808192);
  float* Ssum     = (float*)(p + 85196800);
  float* delta    = xin;  // xin dead after conv; reuse for delta

  pack_kernel<<<8192, 256, 0, stream>>>(skip_w, in_w, out_w, wd2, wd1, wb, wc, A_log,
                                        skipw_bf, inw_bf, outw_bf, wd2_bf, w96, Aneg);
  rmsnorm_kernel<<<2048, 256, 0, stream>>>(resid, norm_w, xn_bf);
  gemm_bt<128, 128, 0><<<dim3(32, 16), 256, 0, stream>>>(
      xn_bf, skipw_bf, inw_bf, 2048, 4096, 1024, 2048,
      (void*)skip_bf, (void*)xin, nullptr, nullptr);
  conv_silu_kernel<<<16384, 256, 0, stream>>>(xin, conv_w, conv_b, xconv, xconv_bf);
  gemm_skinny<<<32, 256, 0, stream>>>(xconv_bf, w96, d1_bf, bc, 2048);
  gemm_bt<128, 128, 1><<<dim3(16, 16), 256, 0, stream>>>(
      d1_bf, wd2_bf, wd2_bf, 2048, 2048, 64, 2048,
      (void*)delta, nullptr, wd2_b, nullptr);
  scan1_kernel<<<dim3(8, 32, 2), 256, 0, stream>>>(delta, xconv, bc, Aneg, hloc, Ssum);
  combine_kernel<<<256, 256, 0, stream>>>(Aneg, Ssum, hloc);
  scan2_kernel<<<dim3(8, 32, 2), 256, 0, stream>>>(delta, xconv, bc, Aneg, hloc,
                                                   skip_bf, W_D, yfin_bf);
  gemm_bt<64, 64, 2><<<dim3(16, 32), 256, 0, stream>>>(
      yfin_bf, outw_bf, outw_bf, 2048, 1024, 2048, 1024,
      (void*)d_out, nullptr, nullptr, resid);
}

// Round 2
// 270.084 us; speedup vs baseline: 1.1291x; 1.1291x over previous
//
#include <hip/hip_runtime.h>
#include <cstdint>

typedef unsigned short u16;
typedef float f32x4 __attribute__((ext_vector_type(4)));
typedef __bf16 bf16x8 __attribute__((ext_vector_type(8)));
typedef u16 u16x8 __attribute__((ext_vector_type(8)));

// ---------- helpers ----------
__device__ __forceinline__ u16 f2bf(float f) {
  uint32_t u = __float_as_uint(f);
  u += 0x7fffu + ((u >> 16) & 1u);   // RNE
  return (u16)(u >> 16);
}
__device__ __forceinline__ float bf2f(u16 s) {
  return __uint_as_float(((uint32_t)s) << 16);
}

// global -> LDS direct copy, 16B per lane
__device__ __forceinline__ void ld16(const u16* g, u16* l) {
  auto* gp = reinterpret_cast<const __attribute__((address_space(1))) u16*>(
      reinterpret_cast<uintptr_t>(g));
  auto* lp = reinterpret_cast<__attribute__((address_space(3))) u16*>(
      static_cast<uint32_t>(reinterpret_cast<uintptr_t>(l)));
  __builtin_amdgcn_global_load_lds(gp, lp, 16, 0, 0);
}

__device__ __forceinline__ f32x4 mfma16(u16x8 a, u16x8 b, f32x4 c) {
  return __builtin_amdgcn_mfma_f32_16x16x32_bf16(
      __builtin_bit_cast(bf16x8, a), __builtin_bit_cast(bf16x8, b), c, 0, 0, 0);
}

__device__ __forceinline__ float sigmoidf_(float x) { return 1.f / (1.f + __expf(-x)); }
__device__ __forceinline__ float siluf_(float x) { return x * sigmoidf_(x); }
__device__ __forceinline__ float softplusf_(float x) {
  return fmaxf(x, 0.f) + log1pf(__expf(-fabsf(x)));
}

// ---------- weight packing ----------
#define PACK_TOT 6651904
__global__ __launch_bounds__(256) void pack_kernel(
    const float* __restrict__ skip_w, const float* __restrict__ in_w,
    const float* __restrict__ out_w, const float* __restrict__ wd2,
    const float* __restrict__ wd1, const float* __restrict__ wb,
    const float* __restrict__ wc, const float* __restrict__ A_log,
    u16* __restrict__ skipw_bf, u16* __restrict__ inw_bf, u16* __restrict__ outw_bf,
    u16* __restrict__ wd2_bf, u16* __restrict__ w96, float* __restrict__ Aneg) {
  int stride = gridDim.x * 256;
  for (int i = blockIdx.x * 256 + threadIdx.x; i < PACK_TOT; i += stride) {
    int j = i;
    if (j < 2097152) { skipw_bf[j] = f2bf(skip_w[j]); continue; } j -= 2097152;
    if (j < 2097152) { inw_bf[j] = f2bf(in_w[j]); continue; } j -= 2097152;
    if (j < 2097152) { outw_bf[j] = f2bf(out_w[j]); continue; } j -= 2097152;
    if (j < 131072)  { wd2_bf[j] = f2bf(wd2[j]); continue; } j -= 131072;
    if (j < 131072)  { w96[j] = f2bf(wd1[j]); continue; } j -= 131072;
    if (j < 32768)   { w96[131072 + j] = f2bf(wb[j]); continue; } j -= 32768;
    if (j < 32768)   { w96[163840 + j] = f2bf(wc[j]); continue; } j -= 32768;
    Aneg[j] = -__expf(A_log[j]);
  }
}

// ---------- RMSNorm ----------
__global__ __launch_bounds__(256) void rmsnorm_kernel(
    const float* __restrict__ x, const float* __restrict__ w, u16* __restrict__ out) {
  int row = blockIdx.x, t = threadIdx.x;
  const float4* xr = (const float4*)(x + (size_t)row * 1024);
  float4 v = xr[t];
  float ss = v.x * v.x + v.y * v.y + v.z * v.z + v.w * v.w;
  for (int o = 32; o > 0; o >>= 1) ss += __shfl_xor(ss, o);
  __shared__ float wsum[4];
  if ((t & 63) == 0) wsum[t >> 6] = ss;
  __syncthreads();
  float tot = wsum[0] + wsum[1] + wsum[2] + wsum[3];
  float rs = rsqrtf(tot * (1.0f / 1024.0f) + 1e-5f);
  float4 wv = ((const float4*)w)[t];
  uint2 pk;
  pk.x = (uint32_t)f2bf(v.x * rs * wv.x) | ((uint32_t)f2bf(v.y * rs * wv.y) << 16);
  pk.y = (uint32_t)f2bf(v.z * rs * wv.z) | ((uint32_t)f2bf(v.w * rs * wv.w) << 16);
  ((uint2*)out)[row * 256 + t] = pk;
}

// ---------- MFMA GEMM: C = A(MxK,bf16) * B(NxK,bf16)^T ----------
// EPI 0: n<Nsplit -> bf16 C0 (ld Nsplit); else fp32 C1 (ld N-Nsplit)   [skip|xin]
// EPI 1: softplus(acc + bias[n]) -> fp32 C0                            [delta]
// EPI 2: addsrc + acc -> fp32 C0                                       [output]
template <int BM, int BN, int EPI>
__global__ __launch_bounds__(256) void gemm_bt(
    const u16* __restrict__ A, const u16* __restrict__ B0, const u16* __restrict__ B1,
    int M, int N, int K, int Nsplit,
    void* __restrict__ C0, void* __restrict__ C1,
    const float* __restrict__ bias, const float* __restrict__ addsrc) {
  constexpr int TM = BM / 32, TN = BN / 32;
  __shared__ __align__(16) u16 sA[BM * 32];
  __shared__ __align__(16) u16 sB[BN * 32];
  const int t = threadIdx.x;
  const int lane = t & 63, wid = t >> 6;
  const int wm = wid >> 1, wn = wid & 1;
  const int mBase = blockIdx.y * BM;
  const int nBase = blockIdx.x * BN;
  const bool hi = (nBase >= Nsplit);
  const u16* Bp = hi ? B1 : B0;
  const int nB0 = nBase - (hi ? Nsplit : 0);
  const int col = lane & 15, quad = lane >> 4;

  f32x4 acc[TM][TN];
#pragma unroll
  for (int i = 0; i < TM; ++i)
#pragma unroll
    for (int j = 0; j < TN; ++j) acc[i][j] = f32x4{0.f, 0.f, 0.f, 0.f};

  for (int k0 = 0; k0 < K; k0 += 32) {
#pragma unroll
    for (int c = t; c < BM * 4; c += 256) {
      int row = c >> 2, k8 = (c & 3) * 8;
      ld16(A + (size_t)(mBase + row) * K + k0 + k8, &sA[c * 8]);
    }
#pragma unroll
    for (int c = t; c < BN * 4; c += 256) {
      int row = c >> 2, k8 = (c & 3) * 8;
      ld16(Bp + (size_t)(nB0 + row) * K + k0 + k8, &sB[c * 8]);
    }
    __syncthreads();
    u16x8 af[TM], bfv[TN];
#pragma unroll
    for (int i = 0; i < TM; ++i)
      af[i] = *(const u16x8*)&sA[(wm * (BM / 2) + i * 16 + col) * 32 + quad * 8];
#pragma unroll
    for (int j = 0; j < TN; ++j)
      bfv[j] = *(const u16x8*)&sB[(wn * (BN / 2) + j * 16 + col) * 32 + quad * 8];
#pragma unroll
    for (int i = 0; i < TM; ++i)
#pragma unroll
      for (int j = 0; j < TN; ++j) acc[i][j] = mfma16(af[i], bfv[j], acc[i][j]);
    __syncthreads();
  }

#pragma unroll
  for (int i = 0; i < TM; ++i) {
#pragma unroll
    for (int j = 0; j < TN; ++j) {
#pragma unroll
      for (int r = 0; r < 4; ++r) {
        int gm = mBase + wm * (BM / 2) + i * 16 + quad * 4 + r;
        int gn = nBase + wn * (BN / 2) + j * 16 + col;
        float v = acc[i][j][r];
        if (EPI == 0) {
          if (gn < Nsplit)
            ((u16*)C0)[(size_t)gm * Nsplit + gn] = f2bf(v);
          else
            ((float*)C1)[(size_t)gm * (N - Nsplit) + (gn - Nsplit)] = v;
        } else if (EPI == 1) {
          ((float*)C0)[(size_t)gm * N + gn] = softplusf_(v + bias[gn]);
        } else {
          ((float*)C0)[(size_t)gm * N + gn] = addsrc[(size_t)gm * N + gn] + v;
        }
      }
    }
  }
}

// ---------- skinny GEMM, split-K: A[2048x2048] * w96[96x2048]^T ----------
// grid (32, 8): x = M-tile of 64 rows, y = K-chunk of 256.
// Writes fp32 partials part[kc][m][96].
__global__ __launch_bounds__(256) void gemm_skinny_splitk(
    const u16* __restrict__ A, const u16* __restrict__ B,
    float* __restrict__ part) {
  __shared__ __align__(16) u16 sA[64 * 32];
  __shared__ __align__(16) u16 sB[96 * 32];
  const int t = threadIdx.x, lane = t & 63, w = t >> 6;
  const int mBase = blockIdx.x * 64;
  const int kBase = blockIdx.y * 256;
  const int col = lane & 15, quad = lane >> 4;
  const int K = 2048;
  f32x4 acc[6];
#pragma unroll
  for (int j = 0; j < 6; ++j) acc[j] = f32x4{0.f, 0.f, 0.f, 0.f};

  for (int k0 = kBase; k0 < kBase + 256; k0 += 32) {
    for (int c = t; c < 640; c += 256) {
      if (c < 256) {
        int row = c >> 2, k8 = (c & 3) * 8;
        ld16(A + (size_t)(mBase + row) * K + k0 + k8, &sA[c * 8]);
      } else {
        int cb = c - 256;
        int row = cb >> 2, k8 = (cb & 3) * 8;
        ld16(B + (size_t)row * K + k0 + k8, &sB[cb * 8]);
      }
    }
    __syncthreads();
    u16x8 af = *(const u16x8*)&sA[(w * 16 + col) * 32 + quad * 8];
#pragma unroll
    for (int j = 0; j < 6; ++j) {
      u16x8 bfv = *(const u16x8*)&sB[(j * 16 + col) * 32 + quad * 8];
      acc[j] = mfma16(af, bfv, acc[j]);
    }
    __syncthreads();
  }
  float* pp = part + (size_t)blockIdx.y * (2048 * 96);
#pragma unroll
  for (int j = 0; j < 6; ++j)
#pragma unroll
    for (int r = 0; r < 4; ++r) {
      int gm = mBase + w * 16 + quad * 4 + r;
      int gn = j * 16 + col;
      pp[gm * 96 + gn] = acc[j][r];
    }
}

// reduce 8 partials; cols 0..63 -> d1 bf16, 64..95 -> bc fp32
__global__ __launch_bounds__(256) void skinny_reduce(
    const float* __restrict__ part, u16* __restrict__ d1_bf,
    float* __restrict__ bc) {
  int i = blockIdx.x * 256 + threadIdx.x;  // < 2048*96 exact (768 blocks)
  float s = 0.f;
#pragma unroll
  for (int kc = 0; kc < 8; ++kc) s += part[kc * 196608 + i];
  int m = i / 96, n = i - m * 96;
  if (n < 64) d1_bf[m * 64 + n] = f2bf(s);
  else bc[m * 32 + n - 64] = s;
}

// ---------- conv (causal depthwise K=4) + SiLU ----------
__global__ __launch_bounds__(256) void conv_silu_kernel(
    const float* __restrict__ xin, const float* __restrict__ conv_w,
    const float* __restrict__ conv_b, float* __restrict__ xconv,
    u16* __restrict__ xconv_bf) {
  int i = blockIdx.x * 256 + threadIdx.x;  // B*L*E exact
  int e = i & 2047;
  int l = (i >> 11) & 1023;
  float4 wv = ((const float4*)conv_w)[e];
  float acc = conv_b[e] + xin[i] * wv.w;
  if (l >= 1) acc += xin[i - 2048] * wv.z;
  if (l >= 2) acc += xin[i - 4096] * wv.y;
  if (l >= 3) acc += xin[i - 6144] * wv.x;
  float s = siluf_(acc);
  xconv[i] = s;
  xconv_bf[i] = f2bf(s);
}

// ---------- SSM scan: pass 1 (local states per 32-chunk) ----------
__global__ __launch_bounds__(256) void scan1_kernel(
    const float* __restrict__ delta, const float* __restrict__ xconv,
    const float* __restrict__ bc, const float* __restrict__ Aneg,
    float* __restrict__ hloc, float* __restrict__ Ssum) {
  int t = threadIdx.x;
  int e = blockIdx.x * 256 + t;
  int c = blockIdx.y, b = blockIdx.z;
  int m0 = b * 1024 + c * 32;
  __shared__ float sBC[1024];
  for (int j = t; j < 1024; j += 256) sBC[j] = bc[m0 * 32 + j];
  float Ar[16], h[16];
#pragma unroll
  for (int n = 0; n < 16; ++n) { Ar[n] = Aneg[e * 16 + n]; h[n] = 0.f; }
  float S = 0.f;
  __syncthreads();
  for (int l = 0; l < 32; ++l) {
    size_t m = (size_t)(m0 + l) * 2048 + e;
    float dt = delta[m], xv = xconv[m];
    S += dt;
    float dx = dt * xv;
    const float* bl = &sBC[l * 32];
#pragma unroll
    for (int n = 0; n < 16; ++n) h[n] = __expf(dt * Ar[n]) * h[n] + dx * bl[n];
  }
  size_t base = ((size_t)(b * 32 + c) * 2048 + e) * 16;
#pragma unroll
  for (int n = 0; n < 16; ++n) hloc[base + n] = h[n];
  Ssum[(b * 32 + c) * 2048 + e] = S;
}

// ---------- scan chunk combine (sequential over 32 chunks) ----------
__global__ __launch_bounds__(256) void combine_kernel(
    const float* __restrict__ Aneg, const float* __restrict__ Ssum,
    float* __restrict__ hloc) {
  int tid = blockIdx.x * 256 + threadIdx.x;  // 65536 = B*E*N
  int b = tid >> 15, r = tid & 32767;
  int e = r >> 4;
  float a = Aneg[r];
  float h = 0.f;
  for (int c = 0; c < 32; ++c) {
    size_t base = (size_t)(b * 32 + c) * 32768 + r;
    float hl = hloc[base];
    float S = Ssum[(b * 32 + c) * 2048 + e];
    hloc[base] = h;  // h_init for this chunk
    h = __expf(a * S) * h + hl;
  }
}

// ---------- scan pass 2: replay with h_init, fused gating epilogue ----------
__global__ __launch_bounds__(256) void scan2_kernel(
    const float* __restrict__ delta, const float* __restrict__ xconv,
    const float* __restrict__ bc, const float* __restrict__ Aneg,
    const float* __restrict__ hloc, const u16* __restrict__ skip_bf,
    const float* __restrict__ W_D, u16* __restrict__ yfin_bf) {
  int t = threadIdx.x;
  int e = blockIdx.x * 256 + t;
  int c = blockIdx.y, b = blockIdx.z;
  int m0 = b * 1024 + c * 32;
  __shared__ float sBC[1024];
  for (int j = t; j < 1024; j += 256) sBC[j] = bc[m0 * 32 + j];
  float Ar[16], h[16];
  size_t hbase = ((size_t)(b * 32 + c) * 2048 + e) * 16;
#pragma unroll
  for (int n = 0; n < 16; ++n) { Ar[n] = Aneg[e * 16 + n]; h[n] = hloc[hbase + n]; }
  float wd = W_D[e];
  __syncthreads();
  for (int l = 0; l < 32; ++l) {
    size_t m = (size_t)(m0 + l) * 2048 + e;
    float dt = delta[m], xv = xconv[m];
    float dx = dt * xv;
    const float* bl = &sBC[l * 32];
    float y = 0.f;
#pragma unroll
    for (int n = 0; n < 16; ++n) {
      h[n] = __expf(dt * Ar[n]) * h[n] + dx * bl[n];
      y += h[n] * bl[16 + n];
    }
    float yv = y + xv * wd;
    float sk = bf2f(skip_bf[m]);
    yv *= sk * sigmoidf_(sk);
    yfin_bf[m] = f2bf(yv);
  }
}

// ---------- launch ----------
extern "C" void kernel_launch(void* const* d_in, const int* in_sizes, int n_in,
                              void* d_out, int out_size, void* d_ws, size_t ws_size,
                              hipStream_t stream) {
  (void)in_sizes; (void)n_in; (void)out_size; (void)ws_size;
  const float* resid  = (const float*)d_in[0];
  const float* norm_w = (const float*)d_in[1];
  const float* skip_w = (const float*)d_in[2];
  const float* in_w   = (const float*)d_in[3];
  const float* conv_w = (const float*)d_in[4];
  const float* conv_b = (const float*)d_in[5];
  const float* wd1    = (const float*)d_in[6];
  const float* wd2    = (const float*)d_in[7];
  const float* wd2_b  = (const float*)d_in[8];
  const float* wb     = (const float*)d_in[9];
  const float* wc     = (const float*)d_in[10];
  const float* A_log  = (const float*)d_in[11];
  const float* W_D    = (const float*)d_in[12];
  const float* out_w  = (const float*)d_in[13];

  char* p = (char*)d_ws;
  u16*   skipw_bf = (u16*)(p + 0);
  u16*   inw_bf   = (u16*)(p + 4194304);
  u16*   outw_bf  = (u16*)(p + 8388608);
  u16*   wd2_bf   = (u16*)(p + 12582912);
  u16*   w96      = (u16*)(p + 12845056);
  float* Aneg     = (float*)(p + 13238272);
  u16*   xn_bf    = (u16*)(p + 13369344);
  u16*   skip_bf  = (u16*)(p + 17563648);
  float* xin      = (float*)(p + 25952256);
  float* xconv    = (float*)(p + 42729472);
  u16*   xconv_bf = (u16*)(p + 59506688);
  u16*   d1_bf    = (u16*)(p + 67895296);
  float* bc       = (float*)(p + 68157440);
  u16*   yfin_bf  = (u16*)(p + 68419584);
  float* hloc     = (float*)(p + 76808192);
  float* Ssum     = (float*)(p + 85196800);
  float* delta    = xin;   // xin dead after conv; reuse for delta
  float* part     = hloc;  // split-K partials; dead before scan1 writes hloc

  pack_kernel<<<8192, 256, 0, stream>>>(skip_w, in_w, out_w, wd2, wd1, wb, wc, A_log,
                                        skipw_bf, inw_bf, outw_bf, wd2_bf, w96, Aneg);
  rmsnorm_kernel<<<2048, 256, 0, stream>>>(resid, norm_w, xn_bf);
  gemm_bt<128, 128, 0><<<dim3(32, 16), 256, 0, stream>>>(
      xn_bf, skipw_bf, inw_bf, 2048, 4096, 1024, 2048,
      (void*)skip_bf, (void*)xin, nullptr, nullptr);
  conv_silu_kernel<<<16384, 256, 0, stream>>>(xin, conv_w, conv_b, xconv, xconv_bf);
  gemm_skinny_splitk<<<dim3(32, 8), 256, 0, stream>>>(xconv_bf, w96, part);
  skinny_reduce<<<768, 256, 0, stream>>>(part, d1_bf, bc);
  gemm_bt<128, 128, 1><<<dim3(16, 16), 256, 0, stream>>>(
      d1_bf, wd2_bf, wd2_bf, 2048, 2048, 64, 2048,
      (void*)delta, nullptr, wd2_b, nullptr);
  scan1_kernel<<<dim3(8, 32, 2), 256, 0, stream>>>(delta, xconv, bc, Aneg, hloc, Ssum);
  combine_kernel<<<256, 256, 0, stream>>>(Aneg, Ssum, hloc);
  scan2_kernel<<<dim3(8, 32, 2), 256, 0, stream>>>(delta, xconv, bc, Aneg, hloc,
                                                   skip_bf, W_D, yfin_bf);
  gemm_bt<64, 64, 2><<<dim3(16, 32), 256, 0, stream>>>(
      yfin_bf, outw_bf, outw_bf, 2048, 1024, 2048, 1024,
      (void*)d_out, nullptr, nullptr, resid);
}

// Round 3
// 262.027 us; speedup vs baseline: 1.1638x; 1.0308x over previous
//
#include <hip/hip_runtime.h>
#include <cstdint>

typedef unsigned short u16;
typedef float f32x4 __attribute__((ext_vector_type(4)));
typedef __bf16 bf16x8 __attribute__((ext_vector_type(8)));
typedef u16 u16x8 __attribute__((ext_vector_type(8)));

// ---------- helpers ----------
__device__ __forceinline__ u16 f2bf(float f) {
  uint32_t u = __float_as_uint(f);
  u += 0x7fffu + ((u >> 16) & 1u);   // RNE
  return (u16)(u >> 16);
}
__device__ __forceinline__ float bf2f(u16 s) {
  return __uint_as_float(((uint32_t)s) << 16);
}

// global -> LDS direct copy, 16B per lane
__device__ __forceinline__ void ld16(const u16* g, u16* l) {
  auto* gp = reinterpret_cast<const __attribute__((address_space(1))) u16*>(
      reinterpret_cast<uintptr_t>(g));
  auto* lp = reinterpret_cast<__attribute__((address_space(3))) u16*>(
      static_cast<uint32_t>(reinterpret_cast<uintptr_t>(l)));
  __builtin_amdgcn_global_load_lds(gp, lp, 16, 0, 0);
}

__device__ __forceinline__ f32x4 mfma16(u16x8 a, u16x8 b, f32x4 c) {
  return __builtin_amdgcn_mfma_f32_16x16x32_bf16(
      __builtin_bit_cast(bf16x8, a), __builtin_bit_cast(bf16x8, b), c, 0, 0, 0);
}

__device__ __forceinline__ float sigmoidf_(float x) { return 1.f / (1.f + __expf(-x)); }
__device__ __forceinline__ float siluf_(float x) { return x * sigmoidf_(x); }
__device__ __forceinline__ float softplusf_(float x) {
  return fmaxf(x, 0.f) + log1pf(__expf(-fabsf(x)));
}

// ---------- weight packing ----------
#define PACK_TOT 6651904
__global__ __launch_bounds__(256) void pack_kernel(
    const float* __restrict__ skip_w, const float* __restrict__ in_w,
    const float* __restrict__ out_w, const float* __restrict__ wd2,
    const float* __restrict__ wd1, const float* __restrict__ wb,
    const float* __restrict__ wc, const float* __restrict__ A_log,
    u16* __restrict__ skipw_bf, u16* __restrict__ inw_bf, u16* __restrict__ outw_bf,
    u16* __restrict__ wd2_bf, u16* __restrict__ w96, float* __restrict__ Aneg) {
  int stride = gridDim.x * 256;
  for (int i = blockIdx.x * 256 + threadIdx.x; i < PACK_TOT; i += stride) {
    int j = i;
    if (j < 2097152) { skipw_bf[j] = f2bf(skip_w[j]); continue; } j -= 2097152;
    if (j < 2097152) { inw_bf[j] = f2bf(in_w[j]); continue; } j -= 2097152;
    if (j < 2097152) { outw_bf[j] = f2bf(out_w[j]); continue; } j -= 2097152;
    if (j < 131072)  { wd2_bf[j] = f2bf(wd2[j]); continue; } j -= 131072;
    if (j < 131072)  { w96[j] = f2bf(wd1[j]); continue; } j -= 131072;
    if (j < 32768)   { w96[131072 + j] = f2bf(wb[j]); continue; } j -= 32768;
    if (j < 32768)   { w96[163840 + j] = f2bf(wc[j]); continue; } j -= 32768;
    Aneg[j] = -__expf(A_log[j]);
  }
}

// ---------- RMSNorm ----------
__global__ __launch_bounds__(256) void rmsnorm_kernel(
    const float* __restrict__ x, const float* __restrict__ w, u16* __restrict__ out) {
  int row = blockIdx.x, t = threadIdx.x;
  const float4* xr = (const float4*)(x + (size_t)row * 1024);
  float4 v = xr[t];
  float ss = v.x * v.x + v.y * v.y + v.z * v.z + v.w * v.w;
  for (int o = 32; o > 0; o >>= 1) ss += __shfl_xor(ss, o);
  __shared__ float wsum[4];
  if ((t & 63) == 0) wsum[t >> 6] = ss;
  __syncthreads();
  float tot = wsum[0] + wsum[1] + wsum[2] + wsum[3];
  float rs = rsqrtf(tot * (1.0f / 1024.0f) + 1e-5f);
  float4 wv = ((const float4*)w)[t];
  uint2 pk;
  pk.x = (uint32_t)f2bf(v.x * rs * wv.x) | ((uint32_t)f2bf(v.y * rs * wv.y) << 16);
  pk.y = (uint32_t)f2bf(v.z * rs * wv.z) | ((uint32_t)f2bf(v.w * rs * wv.w) << 16);
  ((uint2*)out)[row * 256 + t] = pk;
}

// ---------- MFMA GEMM: C = A(MxK,bf16) * B(NxK,bf16)^T ----------
// EPI 0: n<Nsplit -> bf16 C0 (ld Nsplit); else bf16 C1 (ld N-Nsplit)   [skip|xin]
// EPI 1: softplus(acc + bias[n]) -> bf16 C0                            [delta]
// EPI 2: addsrc + acc -> fp32 C0                                       [output]
template <int BM, int BN, int BK, int EPI>
__global__ __launch_bounds__(256) void gemm_bt(
    const u16* __restrict__ A, const u16* __restrict__ B0, const u16* __restrict__ B1,
    int M, int N, int K, int Nsplit,
    void* __restrict__ C0, void* __restrict__ C1,
    const float* __restrict__ bias, const float* __restrict__ addsrc) {
  constexpr int TM = BM / 32, TN = BN / 32;
  constexpr int KC = BK / 8;   // 8-elem chunks per row
  __shared__ __align__(16) u16 sA[BM * BK];
  __shared__ __align__(16) u16 sB[BN * BK];
  const int t = threadIdx.x;
  const int lane = t & 63, wid = t >> 6;
  const int wm = wid >> 1, wn = wid & 1;
  const int mBase = blockIdx.y * BM;
  const int nBase = blockIdx.x * BN;
  const bool hi = (nBase >= Nsplit);
  const u16* Bp = hi ? B1 : B0;
  const int nB0 = nBase - (hi ? Nsplit : 0);
  const int col = lane & 15, quad = lane >> 4;

  f32x4 acc[TM][TN];
#pragma unroll
  for (int i = 0; i < TM; ++i)
#pragma unroll
    for (int j = 0; j < TN; ++j) acc[i][j] = f32x4{0.f, 0.f, 0.f, 0.f};

  for (int k0 = 0; k0 < K; k0 += BK) {
#pragma unroll
    for (int c = t; c < BM * KC; c += 256) {
      int row = c / KC, k8 = (c % KC) * 8;
      ld16(A + (size_t)(mBase + row) * K + k0 + k8, &sA[c * 8]);
    }
#pragma unroll
    for (int c = t; c < BN * KC; c += 256) {
      int row = c / KC, k8 = (c % KC) * 8;
      ld16(Bp + (size_t)(nB0 + row) * K + k0 + k8, &sB[c * 8]);
    }
    __syncthreads();
#pragma unroll
    for (int kk = 0; kk < BK / 32; ++kk) {
      u16x8 af[TM], bfv[TN];
#pragma unroll
      for (int i = 0; i < TM; ++i)
        af[i] = *(const u16x8*)&sA[(wm * (BM / 2) + i * 16 + col) * BK + kk * 32 + quad * 8];
#pragma unroll
      for (int j = 0; j < TN; ++j)
        bfv[j] = *(const u16x8*)&sB[(wn * (BN / 2) + j * 16 + col) * BK + kk * 32 + quad * 8];
#pragma unroll
      for (int i = 0; i < TM; ++i)
#pragma unroll
        for (int j = 0; j < TN; ++j) acc[i][j] = mfma16(af[i], bfv[j], acc[i][j]);
    }
    __syncthreads();
  }

#pragma unroll
  for (int i = 0; i < TM; ++i) {
#pragma unroll
    for (int j = 0; j < TN; ++j) {
#pragma unroll
      for (int r = 0; r < 4; ++r) {
        int gm = mBase + wm * (BM / 2) + i * 16 + quad * 4 + r;
        int gn = nBase + wn * (BN / 2) + j * 16 + col;
        float v = acc[i][j][r];
        if (EPI == 0) {
          if (gn < Nsplit)
            ((u16*)C0)[(size_t)gm * Nsplit + gn] = f2bf(v);
          else
            ((u16*)C1)[(size_t)gm * (N - Nsplit) + (gn - Nsplit)] = f2bf(v);
        } else if (EPI == 1) {
          ((u16*)C0)[(size_t)gm * N + gn] = f2bf(softplusf_(v + bias[gn]));
        } else {
          ((float*)C0)[(size_t)gm * N + gn] = addsrc[(size_t)gm * N + gn] + v;
        }
      }
    }
  }
}

// ---------- skinny GEMM, split-K: A[2048x2048] * w96[96x2048]^T ----------
__global__ __launch_bounds__(256) void gemm_skinny_splitk(
    const u16* __restrict__ A, const u16* __restrict__ B,
    float* __restrict__ part) {
  __shared__ __align__(16) u16 sA[64 * 32];
  __shared__ __align__(16) u16 sB[96 * 32];
  const int t = threadIdx.x, lane = t & 63, w = t >> 6;
  const int mBase = blockIdx.x * 64;
  const int kBase = blockIdx.y * 256;
  const int col = lane & 15, quad = lane >> 4;
  const int K = 2048;
  f32x4 acc[6];
#pragma unroll
  for (int j = 0; j < 6; ++j) acc[j] = f32x4{0.f, 0.f, 0.f, 0.f};

  for (int k0 = kBase; k0 < kBase + 256; k0 += 32) {
    for (int c = t; c < 640; c += 256) {
      if (c < 256) {
        int row = c >> 2, k8 = (c & 3) * 8;
        ld16(A + (size_t)(mBase + row) * K + k0 + k8, &sA[c * 8]);
      } else {
        int cb = c - 256;
        int row = cb >> 2, k8 = (cb & 3) * 8;
        ld16(B + (size_t)row * K + k0 + k8, &sB[cb * 8]);
      }
    }
    __syncthreads();
    u16x8 af = *(const u16x8*)&sA[(w * 16 + col) * 32 + quad * 8];
#pragma unroll
    for (int j = 0; j < 6; ++j) {
      u16x8 bfv = *(const u16x8*)&sB[(j * 16 + col) * 32 + quad * 8];
      acc[j] = mfma16(af, bfv, acc[j]);
    }
    __syncthreads();
  }
  float* pp = part + (size_t)blockIdx.y * (2048 * 96);
#pragma unroll
  for (int j = 0; j < 6; ++j)
#pragma unroll
    for (int r = 0; r < 4; ++r) {
      int gm = mBase + w * 16 + quad * 4 + r;
      int gn = j * 16 + col;
      pp[gm * 96 + gn] = acc[j][r];
    }
}

// reduce 8 partials; cols 0..63 -> d1 bf16, 64..95 -> bc fp32
__global__ __launch_bounds__(256) void skinny_reduce(
    const float* __restrict__ part, u16* __restrict__ d1_bf,
    float* __restrict__ bc) {
  int i = blockIdx.x * 256 + threadIdx.x;  // < 2048*96 exact (768 blocks)
  float s = 0.f;
#pragma unroll
  for (int kc = 0; kc < 8; ++kc) s += part[kc * 196608 + i];
  int m = i / 96, n = i - m * 96;
  if (n < 64) d1_bf[m * 64 + n] = f2bf(s);
  else bc[m * 32 + n - 64] = s;
}

// ---------- conv (causal depthwise K=4) + SiLU, bf16 in/out ----------
__global__ __launch_bounds__(256) void conv_silu_kernel(
    const u16* __restrict__ xin_bf, const float* __restrict__ conv_w,
    const float* __restrict__ conv_b, u16* __restrict__ xconv_bf) {
  int i = blockIdx.x * 256 + threadIdx.x;  // B*L*E exact
  int e = i & 2047;
  int l = (i >> 11) & 1023;
  float4 wv = ((const float4*)conv_w)[e];
  float acc = conv_b[e] + bf2f(xin_bf[i]) * wv.w;
  if (l >= 1) acc += bf2f(xin_bf[i - 2048]) * wv.z;
  if (l >= 2) acc += bf2f(xin_bf[i - 4096]) * wv.y;
  if (l >= 3) acc += bf2f(xin_bf[i - 6144]) * wv.x;
  xconv_bf[i] = f2bf(siluf_(acc));
}

// ---------- SSM scan: pass 1 (local states per 32-chunk) ----------
__global__ __launch_bounds__(256) void scan1_kernel(
    const u16* __restrict__ delta_bf, const u16* __restrict__ xconv_bf,
    const float* __restrict__ bc, const float* __restrict__ Aneg,
    float* __restrict__ hloc, float* __restrict__ Ssum) {
  int t = threadIdx.x;
  int e = blockIdx.x * 256 + t;
  int c = blockIdx.y, b = blockIdx.z;
  int m0 = b * 1024 + c * 32;
  __shared__ float sBC[1024];
  for (int j = t; j < 1024; j += 256) sBC[j] = bc[m0 * 32 + j];
  float Ar[16], h[16];
#pragma unroll
  for (int n = 0; n < 16; ++n) { Ar[n] = Aneg[e * 16 + n]; h[n] = 0.f; }
  float S = 0.f;
  __syncthreads();
  for (int l = 0; l < 32; ++l) {
    size_t m = (size_t)(m0 + l) * 2048 + e;
    float dt = bf2f(delta_bf[m]), xv = bf2f(xconv_bf[m]);
    S += dt;
    float dx = dt * xv;
    const float* bl = &sBC[l * 32];
#pragma unroll
    for (int n = 0; n < 16; ++n) h[n] = __expf(dt * Ar[n]) * h[n] + dx * bl[n];
  }
  size_t base = ((size_t)(b * 32 + c) * 2048 + e) * 16;
#pragma unroll
  for (int n = 0; n < 16; ++n) hloc[base + n] = h[n];
  Ssum[(b * 32 + c) * 2048 + e] = S;
}

// ---------- scan chunk combine (sequential over 32 chunks) ----------
__global__ __launch_bounds__(256) void combine_kernel(
    const float* __restrict__ Aneg, const float* __restrict__ Ssum,
    float* __restrict__ hloc) {
  int tid = blockIdx.x * 256 + threadIdx.x;  // 65536 = B*E*N
  int b = tid >> 15, r = tid & 32767;
  int e = r >> 4;
  float a = Aneg[r];
  float h = 0.f;
  for (int c = 0; c < 32; ++c) {
    size_t base = (size_t)(b * 32 + c) * 32768 + r;
    float hl = hloc[base];
    float S = Ssum[(b * 32 + c) * 2048 + e];
    hloc[base] = h;  // h_init for this chunk
    h = __expf(a * S) * h + hl;
  }
}

// ---------- scan pass 2: replay with h_init, fused gating epilogue ----------
__global__ __launch_bounds__(256) void scan2_kernel(
    const u16* __restrict__ delta_bf, const u16* __restrict__ xconv_bf,
    const float* __restrict__ bc, const float* __restrict__ Aneg,
    const float* __restrict__ hloc, const u16* __restrict__ skip_bf,
    const float* __restrict__ W_D, u16* __restrict__ yfin_bf) {
  int t = threadIdx.x;
  int e = blockIdx.x * 256 + t;
  int c = blockIdx.y, b = blockIdx.z;
  int m0 = b * 1024 + c * 32;
  __shared__ float sBC[1024];
  for (int j = t; j < 1024; j += 256) sBC[j] = bc[m0 * 32 + j];
  float Ar[16], h[16];
  size_t hbase = ((size_t)(b * 32 + c) * 2048 + e) * 16;
#pragma unroll
  for (int n = 0; n < 16; ++n) { Ar[n] = Aneg[e * 16 + n]; h[n] = hloc[hbase + n]; }
  float wd = W_D[e];
  __syncthreads();
  for (int l = 0; l < 32; ++l) {
    size_t m = (size_t)(m0 + l) * 2048 + e;
    float dt = bf2f(delta_bf[m]), xv = bf2f(xconv_bf[m]);
    float dx = dt * xv;
    const float* bl = &sBC[l * 32];
    float y = 0.f;
#pragma unroll
    for (int n = 0; n < 16; ++n) {
      h[n] = __expf(dt * Ar[n]) * h[n] + dx * bl[n];
      y += h[n] * bl[16 + n];
    }
    float yv = y + xv * wd;
    float sk = bf2f(skip_bf[m]);
    yv *= sk * sigmoidf_(sk);
    yfin_bf[m] = f2bf(yv);
  }
}

// ---------- launch ----------
extern "C" void kernel_launch(void* const* d_in, const int* in_sizes, int n_in,
                              void* d_out, int out_size, void* d_ws, size_t ws_size,
                              hipStream_t stream) {
  (void)in_sizes; (void)n_in; (void)out_size; (void)ws_size;
  const float* resid  = (const float*)d_in[0];
  const float* norm_w = (const float*)d_in[1];
  const float* skip_w = (const float*)d_in[2];
  const float* in_w   = (const float*)d_in[3];
  const float* conv_w = (const float*)d_in[4];
  const float* conv_b = (const float*)d_in[5];
  const float* wd1    = (const float*)d_in[6];
  const float* wd2    = (const float*)d_in[7];
  const float* wd2_b  = (const float*)d_in[8];
  const float* wb     = (const float*)d_in[9];
  const float* wc     = (const float*)d_in[10];
  const float* A_log  = (const float*)d_in[11];
  const float* W_D    = (const float*)d_in[12];
  const float* out_w  = (const float*)d_in[13];

  char* p = (char*)d_ws;
  u16*   skipw_bf = (u16*)(p + 0);         //  4 MiB
  u16*   inw_bf   = (u16*)(p + 4194304);   //  4 MiB
  u16*   outw_bf  = (u16*)(p + 8388608);   //  4 MiB
  u16*   wd2_bf   = (u16*)(p + 12582912);  //  256 KiB
  u16*   w96      = (u16*)(p + 12845056);  //  384 KiB
  float* Aneg     = (float*)(p + 13238272);//  128 KiB
  u16*   xn_bf    = (u16*)(p + 13369344);  //  4 MiB
  u16*   skip_bf  = (u16*)(p + 17563648);  //  8 MiB
  u16*   xin_bf   = (u16*)(p + 25952256);  //  8 MiB
  u16*   xconv_bf = (u16*)(p + 34340864);  //  8 MiB
  u16*   delta_bf = (u16*)(p + 42729472);  //  8 MiB
  u16*   d1_bf    = (u16*)(p + 51118080);  //  256 KiB
  float* bc       = (float*)(p + 51380224);//  256 KiB
  u16*   yfin_bf  = (u16*)(p + 51642368);  //  8 MiB
  float* part     = (float*)(p + 60030976);//  6 MiB
  float* hloc     = (float*)(p + 66322432);//  8 MiB
  float* Ssum     = (float*)(p + 74711040);//  512 KiB

  pack_kernel<<<8192, 256, 0, stream>>>(skip_w, in_w, out_w, wd2, wd1, wb, wc, A_log,
                                        skipw_bf, inw_bf, outw_bf, wd2_bf, w96, Aneg);
  rmsnorm_kernel<<<2048, 256, 0, stream>>>(resid, norm_w, xn_bf);
  gemm_bt<128, 128, 32, 0><<<dim3(32, 16), 256, 0, stream>>>(
      xn_bf, skipw_bf, inw_bf, 2048, 4096, 1024, 2048,
      (void*)skip_bf, (void*)xin_bf, nullptr, nullptr);
  conv_silu_kernel<<<16384, 256, 0, stream>>>(xin_bf, conv_w, conv_b, xconv_bf);
  gemm_skinny_splitk<<<dim3(32, 8), 256, 0, stream>>>(xconv_bf, w96, part);
  skinny_reduce<<<768, 256, 0, stream>>>(part, d1_bf, bc);
  gemm_bt<128, 128, 64, 1><<<dim3(16, 16), 256, 0, stream>>>(
      d1_bf, wd2_bf, wd2_bf, 2048, 2048, 64, 2048,
      (void*)delta_bf, nullptr, wd2_b, nullptr);
  scan1_kernel<<<dim3(8, 32, 2), 256, 0, stream>>>(delta_bf, xconv_bf, bc, Aneg,
                                                   hloc, Ssum);
  combine_kernel<<<256, 256, 0, stream>>>(Aneg, Ssum, hloc);
  scan2_kernel<<<dim3(8, 32, 2), 256, 0, stream>>>(delta_bf, xconv_bf, bc, Aneg, hloc,
                                                   skip_bf, W_D, yfin_bf);
  gemm_bt<64, 64, 64, 2><<<dim3(16, 32), 256, 0, stream>>>(
      yfin_bf, outw_bf, outw_bf, 2048, 1024, 2048, 1024,
      (void*)d_out, nullptr, nullptr, resid);
}

// Round 4
// 232.519 us; speedup vs baseline: 1.3115x; 1.1269x over previous
//
#include <hip/hip_runtime.h>
#include <cstdint>

typedef unsigned short u16;
typedef float f32x4 __attribute__((ext_vector_type(4)));
typedef __bf16 bf16x8 __attribute__((ext_vector_type(8)));
typedef u16 u16x8 __attribute__((ext_vector_type(8)));

// ---------- helpers ----------
__device__ __forceinline__ u16 f2bf(float f) {
  uint32_t u = __float_as_uint(f);
  u += 0x7fffu + ((u >> 16) & 1u);   // RNE
  return (u16)(u >> 16);
}
__device__ __forceinline__ float bf2f(u16 s) {
  return __uint_as_float(((uint32_t)s) << 16);
}

// global -> LDS direct copy, 16B per lane
__device__ __forceinline__ void ld16(const u16* g, u16* l) {
  auto* gp = reinterpret_cast<const __attribute__((address_space(1))) u16*>(
      reinterpret_cast<uintptr_t>(g));
  auto* lp = reinterpret_cast<__attribute__((address_space(3))) u16*>(
      static_cast<uint32_t>(reinterpret_cast<uintptr_t>(l)));
  __builtin_amdgcn_global_load_lds(gp, lp, 16, 0, 0);
}

__device__ __forceinline__ f32x4 mfma16(u16x8 a, u16x8 b, f32x4 c) {
  return __builtin_amdgcn_mfma_f32_16x16x32_bf16(
      __builtin_bit_cast(bf16x8, a), __builtin_bit_cast(bf16x8, b), c, 0, 0, 0);
}

__device__ __forceinline__ float sigmoidf_(float x) { return 1.f / (1.f + __expf(-x)); }
__device__ __forceinline__ float siluf_(float x) { return x * sigmoidf_(x); }
__device__ __forceinline__ float softplusf_(float x) {
  return fmaxf(x, 0.f) + log1pf(__expf(-fabsf(x)));
}

// ---------- fused pack (blocks 0..1023, grid-stride) + RMSNorm (blocks 1024..3071) ----------
#define PACK_TOT 6651904
__global__ __launch_bounds__(256) void pack_rms_kernel(
    const float* __restrict__ skip_w, const float* __restrict__ in_w,
    const float* __restrict__ out_w, const float* __restrict__ wd2,
    const float* __restrict__ wd1, const float* __restrict__ wb,
    const float* __restrict__ wc, const float* __restrict__ A_log,
    u16* __restrict__ skipw_bf, u16* __restrict__ inw_bf, u16* __restrict__ outw_bf,
    u16* __restrict__ wd2_bf, u16* __restrict__ w96, float* __restrict__ Aneg,
    const float* __restrict__ resid, const float* __restrict__ norm_w,
    u16* __restrict__ xn_bf) {
  int t = threadIdx.x;
  if (blockIdx.x >= 1024) {
    // RMSNorm on row = blockIdx.x - 1024
    int row = blockIdx.x - 1024;
    const float4* xr = (const float4*)(resid + (size_t)row * 1024);
    float4 v = xr[t];
    float ss = v.x * v.x + v.y * v.y + v.z * v.z + v.w * v.w;
    for (int o = 32; o > 0; o >>= 1) ss += __shfl_xor(ss, o);
    __shared__ float wsum[4];
    if ((t & 63) == 0) wsum[t >> 6] = ss;
    __syncthreads();
    float tot = wsum[0] + wsum[1] + wsum[2] + wsum[3];
    float rs = rsqrtf(tot * (1.0f / 1024.0f) + 1e-5f);
    float4 wv = ((const float4*)norm_w)[t];
    uint2 pk;
    pk.x = (uint32_t)f2bf(v.x * rs * wv.x) | ((uint32_t)f2bf(v.y * rs * wv.y) << 16);
    pk.y = (uint32_t)f2bf(v.z * rs * wv.z) | ((uint32_t)f2bf(v.w * rs * wv.w) << 16);
    ((uint2*)xn_bf)[row * 256 + t] = pk;
    return;
  }
  const int stride = 1024 * 256;
  for (int i = blockIdx.x * 256 + t; i < PACK_TOT; i += stride) {
    int j = i;
    if (j < 2097152) { skipw_bf[j] = f2bf(skip_w[j]); continue; } j -= 2097152;
    if (j < 2097152) { inw_bf[j] = f2bf(in_w[j]); continue; } j -= 2097152;
    if (j < 2097152) { outw_bf[j] = f2bf(out_w[j]); continue; } j -= 2097152;
    if (j < 131072)  { wd2_bf[j] = f2bf(wd2[j]); continue; } j -= 131072;
    if (j < 131072)  { w96[j] = f2bf(wd1[j]); continue; } j -= 131072;
    if (j < 32768)   { w96[131072 + j] = f2bf(wb[j]); continue; } j -= 32768;
    if (j < 32768)   { w96[163840 + j] = f2bf(wc[j]); continue; } j -= 32768;
    Aneg[j] = -__expf(A_log[j]);
  }
}

// ---------- MFMA GEMM: C = A(MxK,bf16) * B(NxK,bf16)^T, K-rotated LDS swizzle ----------
// EPI 0: n<Nsplit -> bf16 C0 (ld Nsplit); else bf16 C1 (ld N-Nsplit)   [skip|xin]
// EPI 1: softplus(acc + bias[n]) -> bf16 C0                            [delta]
// EPI 2: addsrc + acc -> fp32 C0                                       [output]
template <int BM, int BN, int BK, int EPI>
__global__ __launch_bounds__(256) void gemm_bt(
    const u16* __restrict__ A, const u16* __restrict__ B0, const u16* __restrict__ B1,
    int M, int N, int K, int Nsplit,
    void* __restrict__ C0, void* __restrict__ C1,
    const float* __restrict__ bias, const float* __restrict__ addsrc) {
  constexpr int TM = BM / 32, TN = BN / 32;
  constexpr int KC = BK / 8;   // 8-elem chunks per row
  __shared__ __align__(16) u16 sA[BM * BK];
  __shared__ __align__(16) u16 sB[BN * BK];
  const int t = threadIdx.x;
  const int lane = t & 63, wid = t >> 6;
  const int wm = wid >> 1, wn = wid & 1;
  const int mBase = blockIdx.y * BM;
  const int nBase = blockIdx.x * BN;
  const bool hi = (nBase >= Nsplit);
  const u16* Bp = hi ? B1 : B0;
  const int nB0 = nBase - (hi ? Nsplit : 0);
  const int col = lane & 15, quad = lane >> 4;

  f32x4 acc[TM][TN];
#pragma unroll
  for (int i = 0; i < TM; ++i)
#pragma unroll
    for (int j = 0; j < TN; ++j) acc[i][j] = f32x4{0.f, 0.f, 0.f, 0.f};

  for (int k0 = 0; k0 < K; k0 += BK) {
#pragma unroll
    for (int c = t; c < BM * KC; c += 256) {
      int row = c / KC, j = c % KC;
      int k8 = ((j + row) & (KC - 1)) * 8;   // rotate-by-row: lands swizzled in LDS
      ld16(A + (size_t)(mBase + row) * K + k0 + k8, &sA[c * 8]);
    }
#pragma unroll
    for (int c = t; c < BN * KC; c += 256) {
      int row = c / KC, j = c % KC;
      int k8 = ((j + row) & (KC - 1)) * 8;
      ld16(Bp + (size_t)(nB0 + row) * K + k0 + k8, &sB[c * 8]);
    }
    __syncthreads();
#pragma unroll
    for (int kk = 0; kk < BK / 32; ++kk) {
      u16x8 af[TM], bfv[TN];
#pragma unroll
      for (int i = 0; i < TM; ++i) {
        int rowA = wm * (BM / 2) + i * 16 + col;
        af[i] = *(const u16x8*)&sA[rowA * BK + (((kk * 4 + quad) - rowA) & (KC - 1)) * 8];
      }
#pragma unroll
      for (int j = 0; j < TN; ++j) {
        int rowB = wn * (BN / 2) + j * 16 + col;
        bfv[j] = *(const u16x8*)&sB[rowB * BK + (((kk * 4 + quad) - rowB) & (KC - 1)) * 8];
      }
#pragma unroll
      for (int i = 0; i < TM; ++i)
#pragma unroll
        for (int j = 0; j < TN; ++j) acc[i][j] = mfma16(af[i], bfv[j], acc[i][j]);
    }
    __syncthreads();
  }

#pragma unroll
  for (int i = 0; i < TM; ++i) {
#pragma unroll
    for (int j = 0; j < TN; ++j) {
#pragma unroll
      for (int r = 0; r < 4; ++r) {
        int gm = mBase + wm * (BM / 2) + i * 16 + quad * 4 + r;
        int gn = nBase + wn * (BN / 2) + j * 16 + col;
        float v = acc[i][j][r];
        if (EPI == 0) {
          if (gn < Nsplit)
            ((u16*)C0)[(size_t)gm * Nsplit + gn] = f2bf(v);
          else
            ((u16*)C1)[(size_t)gm * (N - Nsplit) + (gn - Nsplit)] = f2bf(v);
        } else if (EPI == 1) {
          ((u16*)C0)[(size_t)gm * N + gn] = f2bf(softplusf_(v + bias[gn]));
        } else {
          ((float*)C0)[(size_t)gm * N + gn] = addsrc[(size_t)gm * N + gn] + v;
        }
      }
    }
  }
}

// ---------- fused conv(K=4)+SiLU + skinny split-K GEMM ----------
// grid (32 mtiles of 64, 8 kchunks of 256). Computes xconv for its (m,e) patch
// in registers (writes xconv_bf as side product + LDS A-tile), then MFMAs
// against w96[96 x 256-chunk] into fp32 partials part[kc][2048][96].
__global__ __launch_bounds__(256) void conv_skinny_kernel(
    const u16* __restrict__ xin_bf, const float* __restrict__ conv_w,
    const float* __restrict__ conv_b, u16* __restrict__ xconv_bf,
    const u16* __restrict__ w96, float* __restrict__ part) {
  constexpr int PAD = 264;                    // sA row stride in u16
  __shared__ __align__(16) u16 sA[64 * PAD];  // ~33 KB conv outputs
  __shared__ __align__(16) u16 sB[96 * 128];  // 24 KB (two K-halves)
  const int t = threadIdx.x, lane = t & 63, w = t >> 6;
  const int mBase = blockIdx.x * 64;
  const int e0 = blockIdx.y * 256;

  // ---- conv phase: thread handles 2 adjacent e-channels x 32 m-rows ----
  {
    const int ep = (t & 127) * 2;   // e_local pair
    const int strip = t >> 7;       // 0..1
    const int ms = mBase + strip * 32;
    const int l0 = ms & 1023;
    const uint32_t* xr = (const uint32_t*)xin_bf;
    size_t base = ((size_t)ms * 2048 + e0 + ep) >> 1;
    int eg = e0 + ep;
    float4 w0 = ((const float4*)conv_w)[eg];
    float4 w1 = ((const float4*)conv_w)[eg + 1];
    float b0 = conv_b[eg], b1 = conv_b[eg + 1];
    uint32_t u;
    u = (l0 >= 1) ? xr[base - 1024] : 0u;
    float h10 = bf2f((u16)u), h11 = bf2f((u16)(u >> 16));
    u = (l0 >= 2) ? xr[base - 2048] : 0u;
    float h20 = bf2f((u16)u), h21 = bf2f((u16)(u >> 16));
    u = (l0 >= 3) ? xr[base - 3072] : 0u;
    float h30 = bf2f((u16)u), h31 = bf2f((u16)(u >> 16));
#pragma unroll 4
    for (int r = 0; r < 32; ++r) {
      uint32_t ux = xr[base + (size_t)r * 1024];
      float x0 = bf2f((u16)ux), x1 = bf2f((u16)(ux >> 16));
      float a0 = b0 + w0.w * x0 + w0.z * h10 + w0.y * h20 + w0.x * h30;
      float a1 = b1 + w1.w * x1 + w1.z * h11 + w1.y * h21 + w1.x * h31;
      a0 = siluf_(a0); a1 = siluf_(a1);
      uint32_t pk = (uint32_t)f2bf(a0) | ((uint32_t)f2bf(a1) << 16);
      ((uint32_t*)xconv_bf)[base + (size_t)r * 1024] = pk;
      *(uint32_t*)&sA[(strip * 32 + r) * PAD + ep] = pk;
      h30 = h20; h31 = h21; h20 = h10; h21 = h11; h10 = x0; h11 = x1;
    }
  }
  // ---- stage B half 0 (k = e0..e0+127), rotated swizzle ----
  for (int c = t; c < 96 * 16; c += 256) {
    int row = c >> 4, j = c & 15;
    int k8 = ((j + row) & 15) * 8;
    ld16(w96 + (size_t)row * 2048 + e0 + k8, &sB[c * 8]);
  }
  __syncthreads();
  const int col = lane & 15, quad = lane >> 4;
  const int rowA = w * 16 + col;
  f32x4 acc[6];
#pragma unroll
  for (int j = 0; j < 6; ++j) acc[j] = f32x4{0.f, 0.f, 0.f, 0.f};
#pragma unroll
  for (int kk = 0; kk < 4; ++kk) {
    u16x8 af = *(const u16x8*)&sA[rowA * PAD + kk * 32 + quad * 8];
#pragma unroll
    for (int j = 0; j < 6; ++j) {
      int rowB = j * 16 + col;
      u16x8 bfv = *(const u16x8*)&sB[rowB * 128 + (((kk * 4 + quad) - rowB) & 15) * 8];
      acc[j] = mfma16(af, bfv, acc[j]);
    }
  }
  __syncthreads();
  // ---- stage B half 1 (k = e0+128..e0+255) ----
  for (int c = t; c < 96 * 16; c += 256) {
    int row = c >> 4, j = c & 15;
    int k8 = ((j + row) & 15) * 8;
    ld16(w96 + (size_t)row * 2048 + e0 + 128 + k8, &sB[c * 8]);
  }
  __syncthreads();
#pragma unroll
  for (int kk = 4; kk < 8; ++kk) {
    u16x8 af = *(const u16x8*)&sA[rowA * PAD + kk * 32 + quad * 8];
#pragma unroll
    for (int j = 0; j < 6; ++j) {
      int rowB = j * 16 + col;
      u16x8 bfv = *(const u16x8*)&sB[rowB * 128 + ((((kk - 4) * 4 + quad) - rowB) & 15) * 8];
      acc[j] = mfma16(af, bfv, acc[j]);
    }
  }
  float* pp = part + (size_t)blockIdx.y * (2048 * 96);
#pragma unroll
  for (int j = 0; j < 6; ++j)
#pragma unroll
    for (int r = 0; r < 4; ++r) {
      int gm = mBase + w * 16 + quad * 4 + r;
      int gn = j * 16 + col;
      pp[gm * 96 + gn] = acc[j][r];
    }
}

// reduce 8 partials; cols 0..63 -> d1 bf16, 64..95 -> bc fp32
__global__ __launch_bounds__(256) void skinny_reduce(
    const float* __restrict__ part, u16* __restrict__ d1_bf,
    float* __restrict__ bc) {
  int i = blockIdx.x * 256 + threadIdx.x;  // < 2048*96 exact (768 blocks)
  float s = 0.f;
#pragma unroll
  for (int kc = 0; kc < 8; ++kc) s += part[kc * 196608 + i];
  int m = i / 96, n = i - m * 96;
  if (n < 64) d1_bf[m * 64 + n] = f2bf(s);
  else bc[m * 32 + n - 64] = s;
}

// ---------- SSM scan: pass 1 (local states per 32-chunk) ----------
__global__ __launch_bounds__(256) void scan1_kernel(
    const u16* __restrict__ delta_bf, const u16* __restrict__ xconv_bf,
    const float* __restrict__ bc, const float* __restrict__ Aneg,
    float* __restrict__ hloc, float* __restrict__ Ssum) {
  int t = threadIdx.x;
  int e = blockIdx.x * 256 + t;
  int c = blockIdx.y, b = blockIdx.z;
  int m0 = b * 1024 + c * 32;
  __shared__ float sBC[1024];
  for (int j = t; j < 1024; j += 256) sBC[j] = bc[m0 * 32 + j];
  float Ar[16], h[16];
#pragma unroll
  for (int n = 0; n < 16; ++n) { Ar[n] = Aneg[e * 16 + n]; h[n] = 0.f; }
  float S = 0.f;
  __syncthreads();
  for (int l = 0; l < 32; ++l) {
    size_t m = (size_t)(m0 + l) * 2048 + e;
    float dt = bf2f(delta_bf[m]), xv = bf2f(xconv_bf[m]);
    S += dt;
    float dx = dt * xv;
    const float* bl = &sBC[l * 32];
#pragma unroll
    for (int n = 0; n < 16; ++n) h[n] = __expf(dt * Ar[n]) * h[n] + dx * bl[n];
  }
  size_t base = ((size_t)(b * 32 + c) * 2048 + e) * 16;
#pragma unroll
  for (int n = 0; n < 16; ++n) hloc[base + n] = h[n];
  Ssum[(b * 32 + c) * 2048 + e] = S;
}

// ---------- scan chunk combine (sequential over 32 chunks) ----------
__global__ __launch_bounds__(256) void combine_kernel(
    const float* __restrict__ Aneg, const float* __restrict__ Ssum,
    float* __restrict__ hloc) {
  int tid = blockIdx.x * 256 + threadIdx.x;  // 65536 = B*E*N
  int b = tid >> 15, r = tid & 32767;
  int e = r >> 4;
  float a = Aneg[r];
  float h = 0.f;
  for (int c = 0; c < 32; ++c) {
    size_t base = (size_t)(b * 32 + c) * 32768 + r;
    float hl = hloc[base];
    float S = Ssum[(b * 32 + c) * 2048 + e];
    hloc[base] = h;  // h_init for this chunk
    h = __expf(a * S) * h + hl;
  }
}

// ---------- scan pass 2: replay with h_init, fused gating epilogue ----------
__global__ __launch_bounds__(256) void scan2_kernel(
    const u16* __restrict__ delta_bf, const u16* __restrict__ xconv_bf,
    const float* __restrict__ bc, const float* __restrict__ Aneg,
    const float* __restrict__ hloc, const u16* __restrict__ skip_bf,
    const float* __restrict__ W_D, u16* __restrict__ yfin_bf) {
  int t = threadIdx.x;
  int e = blockIdx.x * 256 + t;
  int c = blockIdx.y, b = blockIdx.z;
  int m0 = b * 1024 + c * 32;
  __shared__ float sBC[1024];
  for (int j = t; j < 1024; j += 256) sBC[j] = bc[m0 * 32 + j];
  float Ar[16], h[16];
  size_t hbase = ((size_t)(b * 32 + c) * 2048 + e) * 16;
#pragma unroll
  for (int n = 0; n < 16; ++n) { Ar[n] = Aneg[e * 16 + n]; h[n] = hloc[hbase + n]; }
  float wd = W_D[e];
  __syncthreads();
  for (int l = 0; l < 32; ++l) {
    size_t m = (size_t)(m0 + l) * 2048 + e;
    float dt = bf2f(delta_bf[m]), xv = bf2f(xconv_bf[m]);
    float dx = dt * xv;
    const float* bl = &sBC[l * 32];
    float y = 0.f;
#pragma unroll
    for (int n = 0; n < 16; ++n) {
      h[n] = __expf(dt * Ar[n]) * h[n] + dx * bl[n];
      y += h[n] * bl[16 + n];
    }
    float yv = y + xv * wd;
    float sk = bf2f(skip_bf[m]);
    yv *= sk * sigmoidf_(sk);
    yfin_bf[m] = f2bf(yv);
  }
}

// ---------- launch ----------
extern "C" void kernel_launch(void* const* d_in, const int* in_sizes, int n_in,
                              void* d_out, int out_size, void* d_ws, size_t ws_size,
                              hipStream_t stream) {
  (void)in_sizes; (void)n_in; (void)out_size; (void)ws_size;
  const float* resid  = (const float*)d_in[0];
  const float* norm_w = (const float*)d_in[1];
  const float* skip_w = (const float*)d_in[2];
  const float* in_w   = (const float*)d_in[3];
  const float* conv_w = (const float*)d_in[4];
  const float* conv_b = (const float*)d_in[5];
  const float* wd1    = (const float*)d_in[6];
  const float* wd2    = (const float*)d_in[7];
  const float* wd2_b  = (const float*)d_in[8];
  const float* wb     = (const float*)d_in[9];
  const float* wc     = (const float*)d_in[10];
  const float* A_log  = (const float*)d_in[11];
  const float* W_D    = (const float*)d_in[12];
  const float* out_w  = (const float*)d_in[13];

  char* p = (char*)d_ws;
  u16*   skipw_bf = (u16*)(p + 0);         //  4 MiB
  u16*   inw_bf   = (u16*)(p + 4194304);   //  4 MiB
  u16*   outw_bf  = (u16*)(p + 8388608);   //  4 MiB
  u16*   wd2_bf   = (u16*)(p + 12582912);  //  256 KiB
  u16*   w96      = (u16*)(p + 12845056);  //  384 KiB
  float* Aneg     = (float*)(p + 13238272);//  128 KiB
  u16*   xn_bf    = (u16*)(p + 13369344);  //  4 MiB
  u16*   skip_bf  = (u16*)(p + 17563648);  //  8 MiB
  u16*   xin_bf   = (u16*)(p + 25952256);  //  8 MiB
  u16*   xconv_bf = (u16*)(p + 34340864);  //  8 MiB
  u16*   delta_bf = (u16*)(p + 42729472);  //  8 MiB
  u16*   d1_bf    = (u16*)(p + 51118080);  //  256 KiB
  float* bc       = (float*)(p + 51380224);//  256 KiB
  u16*   yfin_bf  = (u16*)(p + 51642368);  //  8 MiB
  float* part     = (float*)(p + 60030976);//  6 MiB
  float* hloc     = (float*)(p + 66322432);//  8 MiB
  float* Ssum     = (float*)(p + 74711040);//  512 KiB

  pack_rms_kernel<<<3072, 256, 0, stream>>>(
      skip_w, in_w, out_w, wd2, wd1, wb, wc, A_log,
      skipw_bf, inw_bf, outw_bf, wd2_bf, w96, Aneg,
      resid, norm_w, xn_bf);
  gemm_bt<128, 128, 64, 0><<<dim3(32, 16), 256, 0, stream>>>(
      xn_bf, skipw_bf, inw_bf, 2048, 4096, 1024, 2048,
      (void*)skip_bf, (void*)xin_bf, nullptr, nullptr);
  conv_skinny_kernel<<<dim3(32, 8), 256, 0, stream>>>(
      xin_bf, conv_w, conv_b, xconv_bf, w96, part);
  skinny_reduce<<<768, 256, 0, stream>>>(part, d1_bf, bc);
  gemm_bt<128, 128, 64, 1><<<dim3(16, 16), 256, 0, stream>>>(
      d1_bf, wd2_bf, wd2_bf, 2048, 2048, 64, 2048,
      (void*)delta_bf, nullptr, wd2_b, nullptr);
  scan1_kernel<<<dim3(8, 32, 2), 256, 0, stream>>>(delta_bf, xconv_bf, bc, Aneg,
                                                   hloc, Ssum);
  combine_kernel<<<256, 256, 0, stream>>>(Aneg, Ssum, hloc);
  scan2_kernel<<<dim3(8, 32, 2), 256, 0, stream>>>(delta_bf, xconv_bf, bc, Aneg, hloc,
                                                   skip_bf, W_D, yfin_bf);
  gemm_bt<64, 64, 128, 2><<<dim3(16, 32), 256, 0, stream>>>(
      yfin_bf, outw_bf, outw_bf, 2048, 1024, 2048, 1024,
      (void*)d_out, nullptr, nullptr, resid);
}